// Round 16
// baseline (265.701 us; speedup 1.0000x reference)
//
#include <hip/hip_runtime.h>
#include <cstdint>
#include <cstddef>

#define B_SZ 16384
#define L_SZ 100
#define K_SZ 4
#define D_SZ 32
#define NBLK_ROUTE 1024
#define WAVES_TOTAL ((NBLK_ROUTE * 256) / 64)   /* 4096 */
#define B_PER_WAVE (B_SZ / WAVES_TOTAL)         /* 4 */
#define NBLK_TBL 2048
#define TBL_ROWS 1000000
#define TBL_TILES (TBL_ROWS/16)                 /* 62500 16-row MFMA tiles */

/* d_ws byte offsets (R7 layout) */
#define WS_WLOG   0u                  /* 400 f32: working copy of routing logits   */
#define WS_E      2048u               /* 400 f32: exp(logit - max_k)               */
#define WS_P      4096u               /* 404 f32: prefix sums P[k][0..L]           */
#define WS_PART   8192u               /* 400*1024 f32 delta partials (1.6MB)       */
#define WS_CAPS   (2u*1024u*1024u)    /* B*K*D f32 = 8 MB                          */
#define WS_TABLE  (16u*1024u*1024u)   /* TBL_ROWS*D f32 = 128 MB (emb @ S table)   */

typedef __attribute__((ext_vector_type(8))) short short8v;
typedef __attribute__((ext_vector_type(4))) float f32x4;

static __device__ __forceinline__ short f2bf(float x) {      /* RNE f32->bf16 */
  unsigned u = __float_as_uint(x);
  unsigned r = (u + 0x7fffu + ((u >> 16) & 1u)) >> 16;
  return (short)r;
}
static __device__ __forceinline__ float bf2f(short h) {
  return __uint_as_float(((unsigned)(unsigned short)h) << 16);
}

/* ---- prep: e[k,l] = exp(logit - max_k), P[k][n] = sum_{l<n} e ---- */
template<bool COPY>
__global__ __launch_bounds__(128) void k_prep(const float* __restrict__ logits,
                                              float* __restrict__ ws) {
  float* __restrict__ wlog = ws + WS_WLOG/4;
  float* __restrict__ e    = ws + WS_E/4;
  float* __restrict__ P    = ws + WS_P/4;
  __shared__ float se[K_SZ*L_SZ];
  const int t = threadIdx.x;
  if (COPY) {
    for (int i = t; i < K_SZ*L_SZ; i += 128) wlog[i] = logits[i];
  }
  const float* __restrict__ src = COPY ? logits : wlog;
  const int k = t >> 5, lane = t & 31;
  float m = -3.4e38f;
  for (int l = lane; l < L_SZ; l += 32) m = fmaxf(m, src[k*L_SZ + l]);
  #pragma unroll
  for (int off = 16; off; off >>= 1) m = fmaxf(m, __shfl_xor(m, off));
  for (int l = lane; l < L_SZ; l += 32) se[k*L_SZ + l] = expf(src[k*L_SZ + l] - m);
  __syncthreads();
  if (t < K_SZ) {
    float s = 0.f;
    P[t*(L_SZ+1)] = 0.f;
    for (int l = 0; l < L_SZ; ++l) { s += se[t*L_SZ + l]; P[t*(L_SZ+1) + l + 1] = s; }
  }
  for (int i = t; i < K_SZ*L_SZ; i += 128) e[i] = se[i];
}

/* ---- table via MFMA: tbl = emb @ S, hi/lo bf16 split (4 terms) for ~f32
   accuracy (rel err ~1.6e-5 << 2e-2 threshold).  Per 16-row tile: 2 coalesced
   1KB loads, ~50 converts, 8 mfma_f32_16x16x32_bf16, 64B-segment stores.
   Fragment layout: A row=lane&15, k=(lane>>4)*8+i; B col=lane&15, same k;
   C/D col=lane&15, row=(lane>>4)*4+j (guide m89-verified). ---- */
__global__ __launch_bounds__(256) void k_table(const float* __restrict__ emb,
                                               const float* __restrict__ S,
                                               float* __restrict__ ws) {
  float* __restrict__ tbl = ws + WS_TABLE/4;
  const int t = threadIdx.x;
  const int w = t >> 6, lane = t & 63;
  const int m = lane & 15, g = lane >> 4;
  /* B fragments: S columns 0..15 (b0) and 16..31 (b1), hi/lo split */
  short8v b0h, b0l, b1h, b1l;
  #pragma unroll
  for (int i = 0; i < 8; ++i) {
    const float s0 = S[(g*8 + i)*D_SZ + m];
    const float s1 = S[(g*8 + i)*D_SZ + 16 + m];
    const short h0 = f2bf(s0); b0h[i] = h0; b0l[i] = f2bf(s0 - bf2f(h0));
    const short h1 = f2bf(s1); b1h[i] = h1; b1l[i] = f2bf(s1 - bf2f(h1));
  }
  const int gw = blockIdx.x*4 + w;
  for (int tile = gw; tile < TBL_TILES; tile += NBLK_TBL*4) {
    const size_t R0 = (size_t)tile * 16;
    const float* __restrict__ ap = emb + (R0 + m)*D_SZ + g*8;
    float a[8];
    *(float4*)(a)     = *(const float4*)(ap);
    *(float4*)(a + 4) = *(const float4*)(ap + 4);
    short8v ah, al;
    #pragma unroll
    for (int i = 0; i < 8; ++i) {
      const short h = f2bf(a[i]); ah[i] = h; al[i] = f2bf(a[i] - bf2f(h));
    }
    f32x4 acc0 = {0.f, 0.f, 0.f, 0.f};
    f32x4 acc1 = {0.f, 0.f, 0.f, 0.f};
    acc0 = __builtin_amdgcn_mfma_f32_16x16x32_bf16(ah, b0h, acc0, 0, 0, 0);
    acc0 = __builtin_amdgcn_mfma_f32_16x16x32_bf16(ah, b0l, acc0, 0, 0, 0);
    acc0 = __builtin_amdgcn_mfma_f32_16x16x32_bf16(al, b0h, acc0, 0, 0, 0);
    acc0 = __builtin_amdgcn_mfma_f32_16x16x32_bf16(al, b0l, acc0, 0, 0, 0);
    acc1 = __builtin_amdgcn_mfma_f32_16x16x32_bf16(ah, b1h, acc1, 0, 0, 0);
    acc1 = __builtin_amdgcn_mfma_f32_16x16x32_bf16(ah, b1l, acc1, 0, 0, 0);
    acc1 = __builtin_amdgcn_mfma_f32_16x16x32_bf16(al, b1h, acc1, 0, 0, 0);
    acc1 = __builtin_amdgcn_mfma_f32_16x16x32_bf16(al, b1l, acc1, 0, 0, 0);
    float* __restrict__ op = tbl + (R0 + (size_t)g*4)*D_SZ + m;
    #pragma unroll
    for (int j = 0; j < 4; ++j) {
      op[j*D_SZ]      = acc0[j];
      op[j*D_SZ + 16] = acc1[j];
    }
  }
}

/* ---- routing iteration (VERBATIM R7): gather rows from the L2/L3-warm table
   into quad-layout registers; Z + squash (+ delta) in registers; NO in-route
   matmuls.  Every __shfl executes with ALL 64 lanes active (R3-R5 lesson). ---- */
template<bool FINAL>
__global__ __launch_bounds__(256) void k_route_g(const int* __restrict__ items,
                                                 const int* __restrict__ seqlen,
                                                 float* __restrict__ ws) {
  const float* __restrict__ tbl = ws + WS_TABLE/4;
  const float* __restrict__ e_g = ws + WS_E/4;
  const float* __restrict__ P_g = ws + WS_P/4;
  float* __restrict__ part  = ws + WS_PART/4;
  float* __restrict__ capsb = ws + WS_CAPS/4;
  __shared__ float s_e[K_SZ*L_SZ];
  __shared__ float s_P[K_SZ*(L_SZ+1)];
  __shared__ float s_delta[4][K_SZ*L_SZ];
  const int t = threadIdx.x;
  const int w = t >> 6, lane = t & 63;
  const int rr = lane >> 3, dq = lane & 7;
  for (int i = t; i < K_SZ*L_SZ; i += 256) s_e[i] = e_g[i];
  for (int i = t; i < K_SZ*(L_SZ+1); i += 256) s_P[i] = P_g[i];
  if (!FINAL) {
    for (int i = lane; i < K_SZ*L_SZ; i += 64) s_delta[w][i] = 0.f;
  }
  __syncthreads();
  const int gw = blockIdx.x*4 + w;
  for (int it = 0; it < B_PER_WAVE; ++it) {
    const int b = gw + it*WAVES_TOTAL;
    const int n = seqlen[b];
    const int it0 = items[b*L_SZ + lane];
    const int it1 = (lane < 36) ? items[b*L_SZ + 64 + lane] : 0;
    float4 reg[13];
    #pragma unroll
    for (int p = 0; p < 13; ++p) {
      const int l = p*8 + rr;
      /* shfl unconditional — all 64 lanes active */
      const int item = (p < 8) ? __shfl(it0, p*8 + rr)
                               : __shfl(it1, p*8 + rr - 64);
      reg[p] = make_float4(0.f, 0.f, 0.f, 0.f);
      const bool need = FINAL ? (l < n) : (l < L_SZ);
      if (need) reg[p] = *(const float4*)(tbl + (size_t)item*D_SZ + dq*4);
    }
    /* ---- Z (guard l < n, p ascending — exact R6 order) ---- */
    float z[K_SZ][4];
    #pragma unroll
    for (int k = 0; k < K_SZ; ++k) { z[k][0]=z[k][1]=z[k][2]=z[k][3]=0.f; }
    #pragma unroll
    for (int p = 0; p < 13; ++p) {
      const int l = p*8 + rr;
      if (l < n) {
        #pragma unroll
        for (int k = 0; k < K_SZ; ++k) {
          const float ek = s_e[k*L_SZ + l];
          z[k][0] = fmaf(ek, reg[p].x, z[k][0]);
          z[k][1] = fmaf(ek, reg[p].y, z[k][1]);
          z[k][2] = fmaf(ek, reg[p].z, z[k][2]);
          z[k][3] = fmaf(ek, reg[p].w, z[k][3]);
        }
      }
    }
    #pragma unroll
    for (int off = 8; off <= 32; off <<= 1) {
      #pragma unroll
      for (int k = 0; k < K_SZ; ++k) {
        z[k][0] += __shfl_xor(z[k][0], off);
        z[k][1] += __shfl_xor(z[k][1], off);
        z[k][2] += __shfl_xor(z[k][2], off);
        z[k][3] += __shfl_xor(z[k][3], off);
      }
    }
    float caps[K_SZ][4];
    #pragma unroll
    for (int k = 0; k < K_SZ; ++k) {
      const float invP = 1.0f / s_P[k*(L_SZ+1) + n];
      float s = 0.f;
      #pragma unroll
      for (int j = 0; j < 4; ++j) { z[k][j] *= invP; s = fmaf(z[k][j], z[k][j], s); }
      s += __shfl_xor(s, 1); s += __shfl_xor(s, 2); s += __shfl_xor(s, 4);
      const float f = s / (1.0f + s) / sqrtf(s + 1e-8f);
      #pragma unroll
      for (int j = 0; j < 4; ++j) caps[k][j] = z[k][j] * f;
    }
    if (FINAL) {
      if (rr == 0) {
        #pragma unroll
        for (int k = 0; k < K_SZ; ++k)
          *(float4*)(capsb + ((size_t)b*K_SZ + k)*D_SZ + dq*4) =
            make_float4(caps[k][0], caps[k][1], caps[k][2], caps[k][3]);
      }
    } else {
      /* ---- delta over ALL 100 rows, from held registers ---- */
      #pragma unroll
      for (int p = 0; p < 13; ++p) {
        const int l = p*8 + rr;
        float dot[K_SZ] = {0.f, 0.f, 0.f, 0.f};
        if (l < L_SZ) {
          #pragma unroll
          for (int k = 0; k < K_SZ; ++k)
            dot[k] = fmaf(reg[p].x, caps[k][0],
                     fmaf(reg[p].y, caps[k][1],
                     fmaf(reg[p].z, caps[k][2],
                          reg[p].w * caps[k][3])));
        }
        #pragma unroll
        for (int k = 0; k < K_SZ; ++k) {
          dot[k] += __shfl_xor(dot[k], 1);
          dot[k] += __shfl_xor(dot[k], 2);
          dot[k] += __shfl_xor(dot[k], 4);
        }
        if (dq == 0 && l < L_SZ) {
          #pragma unroll
          for (int k = 0; k < K_SZ; ++k) s_delta[w][k*L_SZ + l] += dot[k];
        }
      }
    }
  }
  if (!FINAL) {
    __syncthreads();
    for (int i = t; i < K_SZ*L_SZ; i += 256)
      part[(size_t)i*NBLK_ROUTE + blockIdx.x] =
        s_delta[0][i] + s_delta[1][i] + s_delta[2][i] + s_delta[3][i];
  }
}

/* ---- reduce delta partials into wlog ---- */
__global__ __launch_bounds__(256) void k_reduce(float* __restrict__ ws) {
  const float* __restrict__ part = ws + WS_PART/4;
  float* __restrict__ wlog = ws + WS_WLOG/4;
  const int kl = blockIdx.x, t = threadIdx.x;
  float s = 0.f;
  for (int i = t; i < NBLK_ROUTE; i += 256) s += part[(size_t)kl*NBLK_ROUTE + i];
  #pragma unroll
  for (int off = 32; off; off >>= 1) s += __shfl_xor(s, off);
  __shared__ float sw[4];
  if ((t & 63) == 0) sw[t >> 6] = s;
  __syncthreads();
  if (t == 0) wlog[kl] += sw[0] + sw[1] + sw[2] + sw[3];
}

/* ---- MLP + label-aware argmax select; one lane per (b,k) ---- */
__global__ __launch_bounds__(256) void k_final(const int* __restrict__ tgt,
                                               const float* __restrict__ emb,
                                               const float* __restrict__ W1,
                                               const float* __restrict__ b1,
                                               const float* __restrict__ W2,
                                               const float* __restrict__ b2,
                                               const float* __restrict__ capsb,
                                               float* __restrict__ out) {
  const int g = blockIdx.x*256 + threadIdx.x;
  const int b = g >> 2, k = g & 3;
  float c[D_SZ];
  {
    const float4* __restrict__ cp = (const float4*)(capsb + (size_t)g * D_SZ);
    #pragma unroll
    for (int q = 0; q < 8; ++q) {
      float4 v = cp[q];
      c[4*q] = v.x; c[4*q+1] = v.y; c[4*q+2] = v.z; c[4*q+3] = v.w;
    }
  }
  float u1[64];
  #pragma unroll
  for (int e2 = 0; e2 < 64; ++e2) u1[e2] = b1[e2];
  #pragma unroll
  for (int j = 0; j < D_SZ; ++j) {
    const float cj = c[j];
    #pragma unroll
    for (int e2 = 0; e2 < 64; ++e2) u1[e2] = fmaf(cj, W1[j*64 + e2], u1[e2]);
  }
  #pragma unroll
  for (int e2 = 0; e2 < 64; ++e2) u1[e2] = fmaxf(u1[e2], 0.f);
  float u2[D_SZ];
  #pragma unroll
  for (int f2 = 0; f2 < D_SZ; ++f2) u2[f2] = b2[f2];
  #pragma unroll
  for (int e2 = 0; e2 < 64; ++e2) {
    const float ue = u1[e2];
    #pragma unroll
    for (int f2 = 0; f2 < D_SZ; ++f2) u2[f2] = fmaf(ue, W2[e2*D_SZ + f2], u2[f2]);
  }
  #pragma unroll
  for (int f2 = 0; f2 < D_SZ; ++f2) u2[f2] = fmaxf(u2[f2], 0.f);
  const int ti = tgt[b];
  const float* __restrict__ tp = emb + (size_t)ti * D_SZ;
  float wgt = 0.f;
  #pragma unroll
  for (int f2 = 0; f2 < D_SZ; ++f2) wgt = fmaf(u2[f2], tp[f2], wgt);
  const float wa = wgt;
  const float wb = __shfl_xor(wa, 1);
  const float wc = __shfl_xor(wa, 2);
  const float wd = __shfl_xor(wb, 2);
  int bestk = -1; float bestv = -3.4e38f;
  #pragma unroll
  for (int kk = 0; kk < K_SZ; ++kk) {
    const int x = kk ^ k;
    const float v = (x == 0) ? wa : (x == 1) ? wb : (x == 2) ? wc : wd;
    if (v > bestv) { bestv = v; bestk = kk; }   /* strict > == np.argmax first-max */
  }
  if (bestk == k) {
    float4* __restrict__ op = (float4*)(out + (size_t)b * D_SZ);
    #pragma unroll
    for (int q = 0; q < 8; ++q)
      op[q] = make_float4(u2[4*q], u2[4*q+1], u2[4*q+2], u2[4*q+3]);
  }
}

extern "C" void kernel_launch(void* const* d_in, const int* in_sizes, int n_in,
                              void* d_out, int out_size, void* d_ws, size_t ws_size,
                              hipStream_t stream) {
  const int*   items  = (const int*)d_in[0];
  const int*   tgt    = (const int*)d_in[1];
  const int*   seqlen = (const int*)d_in[2];
  const float* emb    = (const float*)d_in[3];
  const float* S      = (const float*)d_in[4];
  const float* logits = (const float*)d_in[5];
  const float* W1     = (const float*)d_in[6];
  const float* b1     = (const float*)d_in[7];
  const float* W2     = (const float*)d_in[8];
  const float* b2     = (const float*)d_in[9];
  float* out = (float*)d_out;
  float* ws  = (float*)d_ws;

  k_prep<true><<<1, 128, 0, stream>>>(logits, ws);
  k_table<<<NBLK_TBL, 256, 0, stream>>>(emb, S, ws);              /* emb @ S via MFMA */

  k_route_g<false><<<NBLK_ROUTE, 256, 0, stream>>>(items, seqlen, ws); /* iter 1 */
  k_reduce<<<K_SZ*L_SZ, 256, 0, stream>>>(ws);
  k_prep<false><<<1, 128, 0, stream>>>(logits, ws);

  k_route_g<false><<<NBLK_ROUTE, 256, 0, stream>>>(items, seqlen, ws); /* iter 2 */
  k_reduce<<<K_SZ*L_SZ, 256, 0, stream>>>(ws);
  k_prep<false><<<1, 128, 0, stream>>>(logits, ws);

  k_route_g<true><<<NBLK_ROUTE, 256, 0, stream>>>(items, seqlen, ws);  /* iter 3 */
  k_final<<<(B_SZ*K_SZ)/256, 256, 0, stream>>>(tgt, emb, W1, b1, W2, b2,
                                               ws + WS_CAPS/4, out);
}